// Round 1
// baseline (3092.356 us; speedup 1.0000x reference)
//
#include <hip/hip_runtime.h>
#include <hip/hip_fp16.h>

typedef _Float16 half8 __attribute__((ext_vector_type(8)));
typedef float floatx4 __attribute__((ext_vector_type(4)));

#define T_STEPS 30
#define BATCH   256
#define HID     1024
#define LAYERS  4
#define N4H     4096
#define K2      2048

#define BM 64
#define BN 64
#define BK 64
#define LDT 72   // padded LDS row stride for As/Bs (f16 elems): 144B, 16B-aligned, 2-way banks
#define ZLD 65   // padded zs row stride (f32 elems)

// ---------- one-time prep: weights [L][H][4H] f32 (kernel & rec_kernel)
// -> WRt [L][4096 q][2048 k] f16, transposed, gate-interleaved rows q = 4n + gate,
// with W in k[0,1024) and R in k[1024,2048).
__global__ void transpose_weights(const float* __restrict__ Wk,
                                  const float* __restrict__ Wr,
                                  _Float16* __restrict__ wrt) {
    __shared__ float tile[32][33];
    const int zc = blockIdx.z;          // 0..7 = layer*2 + mat
    const int j = zc >> 1, mat = zc & 1;
    const float* src = (mat == 0 ? Wk : Wr) + (size_t)j * HID * N4H;
    _Float16* dst = wrt + (size_t)j * N4H * K2 + mat * HID;
    const int c0 = blockIdx.x * 32;     // source column tile (over 4H)
    const int k0 = blockIdx.y * 32;     // source row tile (over H = k dim)
    const int tx = threadIdx.x, ty = threadIdx.y;
    for (int i = ty; i < 32; i += 8)
        tile[i][tx] = src[(size_t)(k0 + i) * N4H + (c0 + tx)];
    __syncthreads();
    for (int o = ty; o < 32; o += 8) {
        const int c = c0 + o;                            // c = gate*1024 + n
        const int q = ((c & (HID - 1)) << 2) | (c >> 10); // q = 4n + gate
        dst[(size_t)q * K2 + (k0 + tx)] = (_Float16)tile[tx][o];
    }
}

// ---------- inputs f32 -> f16, 8 elems/thread
__global__ void cvt_inputs(const float* __restrict__ in, _Float16* __restrict__ out) {
    const size_t i = ((size_t)blockIdx.x * 256 + threadIdx.x) * 8;
    const float4 a = *(const float4*)(in + i);
    const float4 b = *(const float4*)(in + i + 4);
    half8 v;
    v[0] = (_Float16)a.x; v[1] = (_Float16)a.y; v[2] = (_Float16)a.z; v[3] = (_Float16)a.w;
    v[4] = (_Float16)b.x; v[5] = (_Float16)b.y; v[6] = (_Float16)b.z; v[7] = (_Float16)b.w;
    *(half8*)(out + i) = v;
}

// ---------- fused LSTM cell: z = X@W + H@R, gates, state update
// grid (64, 4): blockIdx.x -> 64-wide q tile (16 hidden units x 4 gates),
// blockIdx.y -> 64-row m tile. 512 threads = 8 waves, each wave: 32m x 16q.
__global__ __launch_bounds__(512) void lstm_cell(
    const _Float16* __restrict__ X,      // [256,1024] f16 (inputs slice or prev-layer c)
    const _Float16* __restrict__ Hrec,   // [256,1024] f16 recurrent h (prev t)
    const _Float16* __restrict__ WR,     // [4096][2048] f16 for this layer
    const float*    __restrict__ bias_j, // [4096] f32, gate-major (orig layout)
    float*          __restrict__ c_master, // [256,1024] f32
    _Float16*       __restrict__ c_out,    // [256,1024] f16 (next layer's X)
    _Float16*       __restrict__ h_out)    // [256,1024] f16 (next t's Hrec)
{
    __shared__ __align__(16) char smem[2 * BM * LDT * sizeof(_Float16)]; // 18432 B
    _Float16* As = (_Float16*)smem;
    _Float16* Bs = (_Float16*)(smem + BM * LDT * sizeof(_Float16));
    float* zs = (float*)smem;            // reused after GEMM: [64][ZLD] = 16640 B

    const int tid  = threadIdx.x;
    const int wv   = tid >> 6, lane = tid & 63;
    const int quad = lane >> 4, l16 = lane & 15;
    const int m0 = blockIdx.y * BM;
    const int q0 = blockIdx.x * BN;
    const int colw = (wv & 3) * 16;      // wave's col offset within tile
    const int roww = (wv >> 2) * 32;     // wave's row offset within tile

    floatx4 acc[2];
    #pragma unroll
    for (int r = 0; r < 2; ++r)
        #pragma unroll
        for (int e = 0; e < 4; ++e) acc[r][e] = 0.f;

    const int srow = tid >> 3;           // 0..63
    const int scol = (tid & 7) << 3;     // 0,8,..,56

    for (int kc = 0; kc < K2; kc += BK) {
        const _Float16* Asrc = (kc < HID) ? (X + kc) : (Hrec + (kc - HID));
        *(half8*)&As[srow * LDT + scol] =
            *(const half8*)&Asrc[(size_t)(m0 + srow) * HID + scol];
        *(half8*)&Bs[srow * LDT + scol] =
            *(const half8*)&WR[(size_t)(q0 + srow) * K2 + kc + scol];
        __syncthreads();
        #pragma unroll
        for (int ks = 0; ks < BK; ks += 32) {
            // B[k][n]: lane holds k = ks+quad*8+j, n = colw+l16
            half8 bfrag = *(const half8*)&Bs[(colw + l16) * LDT + ks + quad * 8];
            #pragma unroll
            for (int r = 0; r < 2; ++r) {
                // A[m][k]: lane holds m = roww+r*16+l16, k = ks+quad*8+j
                half8 afrag = *(const half8*)&As[(roww + r * 16 + l16) * LDT + ks + quad * 8];
                acc[r] = __builtin_amdgcn_mfma_f32_16x16x32_f16(afrag, bfrag, acc[r], 0, 0, 0);
            }
        }
        __syncthreads();
    }

    // C/D layout (verified m89/m91): col = lane&15, row = quad*4 + reg
    #pragma unroll
    for (int r = 0; r < 2; ++r)
        #pragma unroll
        for (int e = 0; e < 4; ++e)
            zs[(roww + r * 16 + quad * 4 + e) * ZLD + colw + l16] = acc[r][e];
    __syncthreads();

    // epilogue: this block covers m in [m0,m0+64), n in [16*bx, 16*bx+16)
    const int nl = tid & 15;
    const int mb = tid >> 4;             // 0..31
    const int n  = blockIdx.x * 16 + nl;
    const float bi = bias_j[n];
    const float bf = bias_j[HID + n];
    const float bg = bias_j[2 * HID + n];
    const float bo = bias_j[3 * HID + n];
    #pragma unroll
    for (int mi = 0; mi < 2; ++mi) {
        const int ml = mb + mi * 32;
        const int m  = m0 + ml;
        const float zi = zs[ml * ZLD + 4 * nl + 0] + bi;
        const float zf = zs[ml * ZLD + 4 * nl + 1] + bf;
        const float zg = zs[ml * ZLD + 4 * nl + 2] + bg;
        const float zo = zs[ml * ZLD + 4 * nl + 3] + bo;
        const float ig = 1.f / (1.f + __expf(-zi));
        const float fg = 1.f / (1.f + __expf(-zf));
        const float gg = tanhf(zg);
        const float og = 1.f / (1.f + __expf(-zo));
        const size_t idx = (size_t)m * HID + n;
        const float c = fg * c_master[idx] + ig * gg;
        const float h = og * tanhf(c);
        c_master[idx] = c;
        c_out[idx] = (_Float16)c;
        h_out[idx] = (_Float16)h;
    }
}

extern "C" void kernel_launch(void* const* d_in, const int* in_sizes, int n_in,
                              void* d_out, int out_size, void* d_ws, size_t ws_size,
                              hipStream_t stream) {
    const float* inputs     = (const float*)d_in[0]; // [30,256,1024]
    const float* kernel_    = (const float*)d_in[1]; // [4,1024,4096]
    const float* rec_kernel = (const float*)d_in[2]; // [4,1024,4096]
    const float* bias       = (const float*)d_in[3]; // [4,4096]
    float* out = (float*)d_out;                      // [256,1024]

    char* ws = (char*)d_ws;
    // ws layout (all 256B-aligned offsets):
    _Float16* WRt      = (_Float16*)(ws);                    // 67,108,864 B
    _Float16* Xf       = (_Float16*)(ws + 67108864);         // 15,728,640 B
    float*    c_master = (float*)   (ws + 82837504);         //  4,194,304 B
    _Float16* c_f16    = (_Float16*)(ws + 87031808);         //  2,097,152 B
    _Float16* h_f16    = (_Float16*)(ws + 89128960);         //  4,194,304 B (2 bufs)
    // total 93,323,264 B

    const size_t BH = (size_t)BATCH * HID;

    // zero the states (ws is poisoned 0xAA before every launch)
    hipMemsetAsync(c_master, 0, LAYERS * BH * sizeof(float), stream);
    hipMemsetAsync(h_f16, 0, 2 * LAYERS * BH * sizeof(_Float16), stream);

    transpose_weights<<<dim3(N4H / 32, HID / 32, LAYERS * 2), dim3(32, 8), 0, stream>>>(
        kernel_, rec_kernel, WRt);
    cvt_inputs<<<(T_STEPS * BATCH * HID) / 8 / 256, 256, 0, stream>>>(inputs, Xf);

    for (int t = 0; t < T_STEPS; ++t) {
        const int wb = t & 1, rb = wb ^ 1;   // h double-buffer: read prev-t, write cur-t
        for (int j = 0; j < LAYERS; ++j) {
            const _Float16* X = (j == 0) ? (Xf + (size_t)t * BH)
                                         : (c_f16 + (size_t)(j - 1) * BH);
            lstm_cell<<<dim3(N4H / BN, BATCH / BM), 512, 0, stream>>>(
                X,
                h_f16 + ((size_t)rb * LAYERS + j) * BH,
                WRt + (size_t)j * N4H * K2,
                bias + (size_t)j * N4H,
                c_master + (size_t)j * BH,
                c_f16 + (size_t)j * BH,
                h_f16 + ((size_t)wb * LAYERS + j) * BH);
        }
    }

    hipMemcpyAsync(out, c_master + 3 * BH, BH * sizeof(float),
                   hipMemcpyDeviceToDevice, stream);
}

// Round 2
// 1447.407 us; speedup vs baseline: 2.1365x; 2.1365x over previous
//
#include <hip/hip_runtime.h>
#include <hip/hip_fp16.h>

typedef _Float16 half8 __attribute__((ext_vector_type(8)));
typedef float floatx4 __attribute__((ext_vector_type(4)));

#define T_STEPS 30
#define BATCH   256
#define HID     1024
#define LAYERS  4
#define N4H     4096
#define K2      2048

#define BM 128
#define BN 64
#define BK 64
#define ZLD 65   // padded zs row stride (f32)

#define AS1(p) ((const __attribute__((address_space(1))) void*)(p))
#define AS3(p) ((__attribute__((address_space(3))) void*)(p))

// ---------- one-time prep: weights [L][H][4H] f32 (kernel & rec_kernel)
// -> WRt [L][4096 q][2048 k] f16, transposed, gate-interleaved rows q = 4n + gate,
// W in k[0,1024), R in k[1024,2048).
__global__ void transpose_weights(const float* __restrict__ Wk,
                                  const float* __restrict__ Wr,
                                  _Float16* __restrict__ wrt) {
    __shared__ float tile[32][33];
    const int zc = blockIdx.z;          // 0..7 = layer*2 + mat
    const int j = zc >> 1, mat = zc & 1;
    const float* src = (mat == 0 ? Wk : Wr) + (size_t)j * HID * N4H;
    _Float16* dst = wrt + (size_t)j * N4H * K2 + mat * HID;
    const int c0 = blockIdx.x * 32;     // source column tile (over 4H)
    const int k0 = blockIdx.y * 32;     // source row tile (over H = k dim)
    const int tx = threadIdx.x, ty = threadIdx.y;
    for (int i = ty; i < 32; i += 8)
        tile[i][tx] = src[(size_t)(k0 + i) * N4H + (c0 + tx)];
    __syncthreads();
    for (int o = ty; o < 32; o += 8) {
        const int c = c0 + o;                             // c = gate*1024 + n
        const int q = ((c & (HID - 1)) << 2) | (c >> 10); // q = 4n + gate
        dst[(size_t)q * K2 + (k0 + tx)] = (_Float16)tile[tx][o];
    }
}

// ---------- inputs f32 -> f16
__global__ void cvt_inputs(const float* __restrict__ in, _Float16* __restrict__ out) {
    const size_t i = ((size_t)blockIdx.x * 256 + threadIdx.x) * 8;
    const float4 a = *(const float4*)(in + i);
    const float4 b = *(const float4*)(in + i + 4);
    half8 v;
    v[0] = (_Float16)a.x; v[1] = (_Float16)a.y; v[2] = (_Float16)a.z; v[3] = (_Float16)a.w;
    v[4] = (_Float16)b.x; v[5] = (_Float16)b.y; v[6] = (_Float16)b.z; v[7] = (_Float16)b.w;
    *(half8*)(out + i) = v;
}

// ---------- diagonal-batched fused LSTM cells
// grid (64, 2, ncells): x = 64-wide q tile (16 hidden units x 4 gates),
// y = 128-row m tile, z = cell on the anti-diagonal (t+j = diag).
// 256 threads = 4 waves; wave tile 64m x 32n = 4x2 of 16x16x32 MFMA.
// Staging: global_load_lds width=16, XOR granule swizzle (g -> g^(row&7))
// baked into gather addresses (no LDS padding allowed with global_load_lds).
__global__ __launch_bounds__(256) void lstm_diag(
    const _Float16* __restrict__ Xf,      // [30][256][1024] f16
    _Float16*       __restrict__ c_act,   // [2 parity][4][256][1024] f16
    _Float16*       __restrict__ h_act,   // [4][256][1024] f16
    const _Float16* __restrict__ WRt,     // [4][4096][2048] f16
    const float*    __restrict__ bias,    // [4][4096] f32 gate-major
    float*          __restrict__ c_master,// [4][256][1024] f32
    int diag, int packed_t, int packed_j)
{
    const int z = blockIdx.z;
    const int t = (packed_t >> (8 * z)) & 255;
    const int j = (packed_j >> (8 * z)) & 255;
    const size_t BH = (size_t)BATCH * HID;

    const _Float16* X    = (j == 0) ? (Xf + (size_t)t * BH)
                                    : (c_act + ((size_t)((diag - 1) & 1) * LAYERS + (j - 1)) * BH);
    const _Float16* Hrec = h_act + (size_t)j * BH;
    const _Float16* WR   = WRt + (size_t)j * N4H * K2;
    const float* bias_j  = bias + (size_t)j * N4H;
    float* c_m           = c_master + (size_t)j * BH;
    _Float16* c_out      = c_act + ((size_t)(diag & 1) * LAYERS + j) * BH;
    _Float16* h_out      = h_act + (size_t)j * BH;

    __shared__ __align__(16) char smem[BM * ZLD * sizeof(float)]; // 33280 B
    _Float16* As = (_Float16*)smem;                 // 128*64 f16 = 16384 B
    _Float16* Bs = (_Float16*)(smem + 16384);       //  64*64 f16 =  8192 B
    float* zs = (float*)smem;                       // reused post-GEMM

    const int tid  = threadIdx.x;
    const int w    = tid >> 6, lane = tid & 63;
    const int quad = lane >> 4, l16 = lane & 15;
    const int mw = (w & 1) * 64;    // wave row offset in tile
    const int nw = (w >> 1) * 32;   // wave col offset in tile
    const int m0 = blockIdx.y * BM;
    const int q0 = blockIdx.x * BN;

    floatx4 acc[4][2];
    #pragma unroll
    for (int a = 0; a < 4; ++a)
        #pragma unroll
        for (int b = 0; b < 2; ++b)
            #pragma unroll
            for (int e = 0; e < 4; ++e) acc[a][b][e] = 0.f;

    for (int kc = 0; kc < K2; kc += BK) {
        const _Float16* Ag = (kc < HID) ? (X + kc) : (Hrec + (kc - HID));
        __syncthreads();   // prev iter's ds_reads done before LDS overwrite
        // ---- stage A: 1024 granules of 16B; slot s holds (r=s>>3, g=(s&7)^(r&7))
        #pragma unroll
        for (int i = 0; i < 4; ++i) {
            const int slot = i * 256 + w * 64 + lane;
            const int r = slot >> 3;
            const int g = (slot & 7) ^ (r & 7);
            const _Float16* src = Ag + (size_t)(m0 + r) * HID + g * 8;
            __builtin_amdgcn_global_load_lds(AS1(src), AS3(As + (i * 256 + w * 64) * 8), 16, 0, 0);
        }
        // ---- stage B: 512 granules
        #pragma unroll
        for (int i = 0; i < 2; ++i) {
            const int slot = i * 256 + w * 64 + lane;
            const int q = slot >> 3;
            const int g = (slot & 7) ^ (q & 7);
            const _Float16* src = WR + (size_t)(q0 + q) * K2 + kc + g * 8;
            __builtin_amdgcn_global_load_lds(AS1(src), AS3(Bs + (i * 256 + w * 64) * 8), 16, 0, 0);
        }
        __syncthreads();   // vmcnt drained by compiler before barrier

        #pragma unroll
        for (int ks = 0; ks < BK; ks += 32) {
            const int g = (ks >> 3) + quad;           // granule of this frag
            half8 bfrag[2];
            #pragma unroll
            for (int b = 0; b < 2; ++b) {
                const int q = nw + b * 16 + l16;      // B col (lane) index
                bfrag[b] = *(const half8*)&Bs[((q << 3) + (g ^ (q & 7))) * 8];
            }
            #pragma unroll
            for (int a = 0; a < 4; ++a) {
                const int r = mw + a * 16 + l16;      // A row (lane) index
                half8 afrag = *(const half8*)&As[((r << 3) + (g ^ (r & 7))) * 8];
                acc[a][0] = __builtin_amdgcn_mfma_f32_16x16x32_f16(afrag, bfrag[0], acc[a][0], 0, 0, 0);
                acc[a][1] = __builtin_amdgcn_mfma_f32_16x16x32_f16(afrag, bfrag[1], acc[a][1], 0, 0, 0);
            }
        }
    }
    __syncthreads();   // all frag reads done before zs overwrites As/Bs

    // C/D layout (verified m89/m91): col = lane&15, row = quad*4 + reg
    #pragma unroll
    for (int a = 0; a < 4; ++a)
        #pragma unroll
        for (int b = 0; b < 2; ++b)
            #pragma unroll
            for (int e = 0; e < 4; ++e)
                zs[(mw + a * 16 + quad * 4 + e) * ZLD + nw + b * 16 + l16] = acc[a][b][e];
    __syncthreads();

    // epilogue: block covers m in [m0,m0+128), n in [16*bx, 16*bx+16)
    const int nl = tid & 15;
    const int mb = tid >> 4;             // 0..15
    const int n  = blockIdx.x * 16 + nl;
    const float bi = bias_j[n];
    const float bf = bias_j[HID + n];
    const float bg = bias_j[2 * HID + n];
    const float bo = bias_j[3 * HID + n];
    #pragma unroll
    for (int mi = 0; mi < 8; ++mi) {
        const int ml = mb + mi * 16;
        const int m  = m0 + ml;
        const float zi = zs[ml * ZLD + 4 * nl + 0] + bi;
        const float zf = zs[ml * ZLD + 4 * nl + 1] + bf;
        const float zg = zs[ml * ZLD + 4 * nl + 2] + bg;
        const float zo = zs[ml * ZLD + 4 * nl + 3] + bo;
        const float ig = 1.f / (1.f + __expf(-zi));
        const float fg = 1.f / (1.f + __expf(-zf));
        const float gg = tanhf(zg);
        const float og = 1.f / (1.f + __expf(-zo));
        const size_t idx = (size_t)m * HID + n;
        const float c = fg * c_m[idx] + ig * gg;
        const float h = og * tanhf(c);
        c_m[idx] = c;
        c_out[idx] = (_Float16)c;
        h_out[idx] = (_Float16)h;
    }
}

extern "C" void kernel_launch(void* const* d_in, const int* in_sizes, int n_in,
                              void* d_out, int out_size, void* d_ws, size_t ws_size,
                              hipStream_t stream) {
    const float* inputs     = (const float*)d_in[0]; // [30,256,1024]
    const float* kernel_    = (const float*)d_in[1]; // [4,1024,4096]
    const float* rec_kernel = (const float*)d_in[2]; // [4,1024,4096]
    const float* bias       = (const float*)d_in[3]; // [4,4096]
    float* out = (float*)d_out;                      // [256,1024]

    char* ws = (char*)d_ws;
    _Float16* WRt      = (_Float16*)(ws);                 // 67,108,864 B
    _Float16* Xf       = (_Float16*)(ws + 67108864);      // 15,728,640 B
    float*    c_master = (float*)   (ws + 82837504);      //  4,194,304 B
    _Float16* c_f16    = (_Float16*)(ws + 87031808);      //  4,194,304 B (2 parity)
    _Float16* h_f16    = (_Float16*)(ws + 91226112);      //  2,097,152 B
    // total 93,323,264 B (same footprint as round 1, known to fit)

    const size_t BH = (size_t)BATCH * HID;

    hipMemsetAsync(c_master, 0, LAYERS * BH * sizeof(float), stream);
    hipMemsetAsync(h_f16, 0, LAYERS * BH * sizeof(_Float16), stream);

    transpose_weights<<<dim3(N4H / 32, HID / 32, LAYERS * 2), dim3(32, 8), 0, stream>>>(
        kernel_, rec_kernel, WRt);
    cvt_inputs<<<(T_STEPS * BATCH * HID) / 8 / 256, 256, 0, stream>>>(inputs, Xf);

    for (int d = 0; d < T_STEPS + LAYERS - 1; ++d) {
        const int jlo = (d - (T_STEPS - 1)) > 0 ? (d - (T_STEPS - 1)) : 0;
        const int jhi = d < (LAYERS - 1) ? d : (LAYERS - 1);
        const int nc  = jhi - jlo + 1;
        int pt = 0, pj = 0;
        for (int zz = 0; zz < nc; ++zz) {
            const int j = jlo + zz, t = d - j;
            pt |= t << (8 * zz);
            pj |= j << (8 * zz);
        }
        lstm_diag<<<dim3(N4H / BN, BATCH / BM, nc), 256, 0, stream>>>(
            Xf, c_f16, h_f16, WRt, bias, c_master, d, pt, pj);
    }

    hipMemcpyAsync(out, c_master + 3 * BH, BH * sizeof(float),
                   hipMemcpyDeviceToDevice, stream);
}